// Round 8
// baseline (1971.527 us; speedup 1.0000x reference)
//
#include <hip/hip_runtime.h>
#include <hip/hip_bf16.h>

#define N_NODES 100000
#define N_EDGES 3200000
#define E_GROUPS (N_EDGES / 8)   // 8 edges per wave-iteration
#define N_GROUPS (N_NODES / 8)   // 8 nodes per wave-iteration

// weight sub-offsets in g_W
#define EW1_O 0        // 88*32
#define EB1_O 2816     // 32
#define EW2_O 2848     // 32*32
#define EB2_O 3872     // 32
#define NW1_O 3904     // 71*32
#define NB1_O 6176     // 32
#define NW2_O 6208     // 32
#define NB2_O 6240     // 1

__device__ float g_nup[N_NODES * 32];   // 12.8 MB scatter accumulator
__device__ float g_W[6244];             // converted weights
__device__ int   g_flags[2];            // [0]: 1=bf16 floats; [1]: 1=int64 idx

__device__ __forceinline__ float bf2f(unsigned short u) {
    union { unsigned int i; float f; } c;
    c.i = ((unsigned int)u) << 16;
    return c.f;
}

__device__ __forceinline__ float rd_any(const void* p, int i, bool bf) {
    if (bf) return bf2f(((const unsigned short*)p)[i]);
    return ((const float*)p)[i];
}

// tanh via hardware exp2: ~6 VALU inst. validated absmax 9.8e-4 (r6/r7).
__device__ __forceinline__ float fast_tanh(float x) {
    float ax = fabsf(x);
    float e  = __expf(ax * 2.0f);
    float t  = 1.0f - 2.0f / (e + 1.0f);
    return copysignf(t, x);
}

__global__ void detect_kernel(const unsigned short* __restrict__ ew1_raw,
                              const int* __restrict__ ei32) {
    __shared__ int s_ok, s_nzodd;
    if (threadIdx.x == 0) { s_ok = 1; s_nzodd = 0; }
    __syncthreads();
    bool ok = true;
    for (int i = threadIdx.x; i < 2816; i += 256) {
        float v = bf2f(ew1_raw[i]);
        if (!(fabsf(v) <= 0.25f)) ok = false;
    }
    if (!ok) atomicAnd(&s_ok, 0);
    int cnt = 0;
    for (int i = threadIdx.x; i < 2048; i += 256)
        if (ei32[2 * i + 1] != 0) cnt++;
    if (cnt) atomicAdd(&s_nzodd, cnt);
    __syncthreads();
    if (threadIdx.x == 0) {
        g_flags[0] = s_ok;
        g_flags[1] = (s_nzodd < 16) ? 1 : 0;
    }
}

__global__ void zero_nup_kernel() {
    int i = blockIdx.x * 256 + threadIdx.x;
    if (i < N_NODES * 8) ((float4*)g_nup)[i] = make_float4(0.f, 0.f, 0.f, 0.f);
}

__global__ void cvt_weights_kernel(const void* ew1, const void* eb1,
                                   const void* ew2, const void* eb2,
                                   const void* nw1, const void* nb1,
                                   const void* nw2, const void* nb2) {
    bool bf = (g_flags[0] != 0);
    int t = blockIdx.x * blockDim.x + threadIdx.x;
    int S = gridDim.x * blockDim.x;
    for (int i = t; i < 2816; i += S) g_W[EW1_O + i] = rd_any(ew1, i, bf);
    for (int i = t; i < 32;   i += S) g_W[EB1_O + i] = rd_any(eb1, i, bf);
    for (int i = t; i < 1024; i += S) g_W[EW2_O + i] = rd_any(ew2, i, bf);
    for (int i = t; i < 32;   i += S) g_W[EB2_O + i] = rd_any(eb2, i, bf);
    for (int i = t; i < 2272; i += S) g_W[NW1_O + i] = rd_any(nw1, i, bf);
    for (int i = t; i < 32;   i += S) g_W[NB1_O + i] = rd_any(nb1, i, bf);
    for (int i = t; i < 32;   i += S) g_W[NW2_O + i] = rd_any(nw2, i, bf);
    if (t == 0) g_W[NB2_O] = rd_any(nb2, 0, bf);
}

// Wave-cooperative edge MLP, ILP-4 + gather prefetch.
// W1^T in LDS [32][90] (stride 90 % 32 = 26 -> worst 2-way alias = free, m136).
__launch_bounds__(256, 4)
__global__ void edge_kernel(const void* __restrict__ nraw,   // [N,39]
                            const void* __restrict__ eraw,   // [E,10]
                            const int*  __restrict__ ei) {   // [2,E]
    const int lane = threadIdx.x & 63;
    const int wv   = threadIdx.x >> 6;
    const int jcol = lane & 31;
    const int half = lane >> 5;
    const bool bf  = (g_flags[0] != 0);
    const bool i64 = (g_flags[1] != 0);

    __shared__ __align__(16) float s_w1t[32 * 90];           // W1^T padded
    __shared__ __align__(16) float sx[4][4][2][96];          // [wave][s][half][x-row]
    __shared__ __align__(16) float sh[4][4][2][32];          // h rows

    // block-cooperative W1^T fill (g_W is L2-hot)
    for (int i = threadIdx.x; i < 88 * 32; i += 256) {
        int r = i >> 5, j = i & 31;
        s_w1t[j * 90 + r] = g_W[EW1_O + r * 32 + j];
    }
    __syncthreads();  // only barrier in the kernel

    // small register-resident pieces
    float w2c[32];
#pragma unroll
    for (int k = 0; k < 32; k++) w2c[k] = g_W[EW2_O + k * 32 + jcol];
    const float b1 = g_W[EB1_O + jcol];
    const float b2 = g_W[EB2_O + jcol];

    const unsigned short* n16 = (const unsigned short*)nraw;
    const unsigned short* e16 = (const unsigned short*)eraw;
    const float*          n32 = (const float*)nraw;
    const float*          e32 = (const float*)eraw;
    const long long*     ei64 = (const long long*)ei;

    const int gw = blockIdx.x * 4 + wv;
    const int stride = gridDim.x * 4;

    float pre[4][3];
    int   psrc[4];

    // gather one group's inputs into registers
    auto gather = [&](int g) {
#pragma unroll
        for (int s = 0; s < 4; s++) {
            const int eh = g * 8 + half * 4 + s;
            int srch, dsth;
            if (i64) { srch = (int)ei64[eh]; dsth = (int)ei64[N_EDGES + eh]; }
            else     { srch = ei[eh];        dsth = ei[N_EDGES + eh]; }
            if ((unsigned)srch >= N_NODES) srch = 0;
            if ((unsigned)dsth >= N_NODES) dsth = 0;
            psrc[s] = srch;
#pragma unroll
            for (int it = 0; it < 3; it++) {
                int t = jcol + it * 32;
                float v = 0.0f;
                if (t < 39)      v = bf ? bf2f(n16[srch * 39 + t])
                                        : n32[srch * 39 + t];
                else if (t < 49) v = bf ? bf2f(e16[(long long)eh * 10 + (t - 39)])
                                        : e32[(long long)eh * 10 + (t - 39)];
                else if (t < 88) v = bf ? bf2f(n16[dsth * 39 + (t - 49)])
                                        : n32[dsth * 39 + (t - 49)];
                pre[s][it] = v;   // t in [88,96) stays 0 -> zero pad
            }
        }
    };

    if (gw < E_GROUPS) gather(gw);

    for (int g = gw; g < E_GROUPS; g += stride) {
        // commit prefetched x to this wave's LDS rows (stride-1, conflict-free)
        int srcs[4];
#pragma unroll
        for (int s = 0; s < 4; s++) {
            srcs[s] = psrc[s];
#pragma unroll
            for (int it = 0; it < 3; it++)
                sx[wv][s][half][jcol + it * 32] = pre[s][it];
        }
        // issue next group's gathers; they land during the compute below
        int gn = g + stride;
        if (gn < E_GROUPS) gather(gn);

        // layer 1: 4 independent chains; W1 col via ds_read_b128 (2-way max = free)
        float acc0 = b1, acc1 = b1, acc2 = b1, acc3 = b1;
        const float4* wc = (const float4*)&s_w1t[jcol * 90];
#pragma unroll
        for (int q = 0; q < 22; q++) {
            float4 w  = wc[q];
            float4 x0 = ((const float4*)sx[wv][0][half])[q];
            float4 x1 = ((const float4*)sx[wv][1][half])[q];
            float4 x2 = ((const float4*)sx[wv][2][half])[q];
            float4 x3 = ((const float4*)sx[wv][3][half])[q];
            acc0 = fmaf(x0.x, w.x, acc0); acc0 = fmaf(x0.y, w.y, acc0);
            acc0 = fmaf(x0.z, w.z, acc0); acc0 = fmaf(x0.w, w.w, acc0);
            acc1 = fmaf(x1.x, w.x, acc1); acc1 = fmaf(x1.y, w.y, acc1);
            acc1 = fmaf(x1.z, w.z, acc1); acc1 = fmaf(x1.w, w.w, acc1);
            acc2 = fmaf(x2.x, w.x, acc2); acc2 = fmaf(x2.y, w.y, acc2);
            acc2 = fmaf(x2.z, w.z, acc2); acc2 = fmaf(x2.w, w.w, acc2);
            acc3 = fmaf(x3.x, w.x, acc3); acc3 = fmaf(x3.y, w.y, acc3);
            acc3 = fmaf(x3.z, w.z, acc3); acc3 = fmaf(x3.w, w.w, acc3);
        }
        sh[wv][0][half][jcol] = fast_tanh(acc0);
        sh[wv][1][half][jcol] = fast_tanh(acc1);
        sh[wv][2][half][jcol] = fast_tanh(acc2);
        sh[wv][3][half][jcol] = fast_tanh(acc3);

        // layer 2 (w2 column register-resident)
        float a0 = b2, a1 = b2, a2 = b2, a3 = b2;
#pragma unroll
        for (int q = 0; q < 8; q++) {
            float4 h0 = ((const float4*)sh[wv][0][half])[q];
            float4 h1 = ((const float4*)sh[wv][1][half])[q];
            float4 h2 = ((const float4*)sh[wv][2][half])[q];
            float4 h3 = ((const float4*)sh[wv][3][half])[q];
            a0 = fmaf(h0.x, w2c[4*q+0], a0); a0 = fmaf(h0.y, w2c[4*q+1], a0);
            a0 = fmaf(h0.z, w2c[4*q+2], a0); a0 = fmaf(h0.w, w2c[4*q+3], a0);
            a1 = fmaf(h1.x, w2c[4*q+0], a1); a1 = fmaf(h1.y, w2c[4*q+1], a1);
            a1 = fmaf(h1.z, w2c[4*q+2], a1); a1 = fmaf(h1.w, w2c[4*q+3], a1);
            a2 = fmaf(h2.x, w2c[4*q+0], a2); a2 = fmaf(h2.y, w2c[4*q+1], a2);
            a2 = fmaf(h2.z, w2c[4*q+2], a2); a2 = fmaf(h2.w, w2c[4*q+3], a2);
            a3 = fmaf(h3.x, w2c[4*q+0], a3); a3 = fmaf(h3.y, w2c[4*q+1], a3);
            a3 = fmaf(h3.z, w2c[4*q+2], a3); a3 = fmaf(h3.w, w2c[4*q+3], a3);
        }
        // coalesced wave-atomics: 2 edges x 32 contiguous dwords each
        atomicAdd(&g_nup[srcs[0] * 32 + jcol], fast_tanh(a0));
        atomicAdd(&g_nup[srcs[1] * 32 + jcol], fast_tanh(a1));
        atomicAdd(&g_nup[srcs[2] * 32 + jcol], fast_tanh(a2));
        atomicAdd(&g_nup[srcs[3] * 32 + jcol], fast_tanh(a3));
    }
}

// Wave-cooperative node MLP, ILP-4; NW1^T in LDS [32][76] (stride 76%32=12 -> 4-way on
// 18 reads, minor). Node loads are sequential (no random gather) -> no prefetch needed.
__launch_bounds__(256, 4)
__global__ void node_kernel(const void* __restrict__ nraw,
                            float* __restrict__ out) {
    const int lane = threadIdx.x & 63;
    const int wv   = threadIdx.x >> 6;
    const int jcol = lane & 31;
    const int half = lane >> 5;
    const bool bf  = (g_flags[0] != 0);

    __shared__ __align__(16) float s_w1t[32 * 76];
    __shared__ __align__(16) float sx[4][4][2][72];  // [nup(32)|n(39)|pad]

    for (int i = threadIdx.x; i < 72 * 32; i += 256) {
        int r = i >> 5, j = i & 31;
        s_w1t[j * 76 + r] = (r < 71) ? g_W[NW1_O + r * 32 + j] : 0.0f;
    }
    __syncthreads();

    const float w2e = g_W[NW2_O + jcol];
    const float b1  = g_W[NB1_O + jcol];
    const float b2  = g_W[NB2_O];

    const unsigned short* n16 = (const unsigned short*)nraw;
    const float*          n32 = (const float*)nraw;

    int gw = blockIdx.x * 4 + wv;
    int stride = gridDim.x * 4;
    for (int g = gw; g < N_GROUPS; g += stride) {
        const int id0 = g * 8 + half * 4;
#pragma unroll
        for (int s = 0; s < 4; s++) {
            const int id = id0 + s;
#pragma unroll
            for (int it = 0; it < 3; it++) {
                int t = jcol + it * 32;
                if (t < 72) {
                    float v;
                    if (t < 32)      v = g_nup[id * 32 + t];
                    else if (t < 71) v = bf ? bf2f(n16[id * 39 + (t - 32)])
                                            : n32[id * 39 + (t - 32)];
                    else             v = 0.0f;
                    sx[wv][s][half][t] = v;
                }
            }
        }
        float acc0 = b1, acc1 = b1, acc2 = b1, acc3 = b1;
        const float4* wc = (const float4*)&s_w1t[jcol * 76];
#pragma unroll
        for (int q = 0; q < 18; q++) {
            float4 w  = wc[q];
            float4 x0 = ((const float4*)sx[wv][0][half])[q];
            float4 x1 = ((const float4*)sx[wv][1][half])[q];
            float4 x2 = ((const float4*)sx[wv][2][half])[q];
            float4 x3 = ((const float4*)sx[wv][3][half])[q];
            acc0 = fmaf(x0.x, w.x, acc0); acc0 = fmaf(x0.y, w.y, acc0);
            acc0 = fmaf(x0.z, w.z, acc0); acc0 = fmaf(x0.w, w.w, acc0);
            acc1 = fmaf(x1.x, w.x, acc1); acc1 = fmaf(x1.y, w.y, acc1);
            acc1 = fmaf(x1.z, w.z, acc1); acc1 = fmaf(x1.w, w.w, acc1);
            acc2 = fmaf(x2.x, w.x, acc2); acc2 = fmaf(x2.y, w.y, acc2);
            acc2 = fmaf(x2.z, w.z, acc2); acc2 = fmaf(x2.w, w.w, acc2);
            acc3 = fmaf(x3.x, w.x, acc3); acc3 = fmaf(x3.y, w.y, acc3);
            acc3 = fmaf(x3.z, w.z, acc3); acc3 = fmaf(x3.w, w.w, acc3);
        }
        float t0 = fast_tanh(acc0) * w2e;
        float t1 = fast_tanh(acc1) * w2e;
        float t2 = fast_tanh(acc2) * w2e;
        float t3 = fast_tanh(acc3) * w2e;
#pragma unroll
        for (int m = 1; m < 32; m <<= 1) {
            t0 += __shfl_xor(t0, m, 64);
            t1 += __shfl_xor(t1, m, 64);
            t2 += __shfl_xor(t2, m, 64);
            t3 += __shfl_xor(t3, m, 64);
        }
        if (jcol == 0) {
            out[id0 + 0] = t0 + b2;
            out[id0 + 1] = t1 + b2;
            out[id0 + 2] = t2 + b2;
            out[id0 + 3] = t3 + b2;
        }
    }
}

extern "C" void kernel_launch(void* const* d_in, const int* in_sizes, int n_in,
                              void* d_out, int out_size, void* d_ws, size_t ws_size,
                              hipStream_t stream) {
    const void* n_raw = d_in[0];
    const void* e_raw = d_in[1];
    const int*  ei    = (const int*)d_in[2];
    // d_in[3] = batch (unused)

    detect_kernel<<<1, 256, 0, stream>>>((const unsigned short*)d_in[4], ei);
    zero_nup_kernel<<<(N_NODES * 8 + 255) / 256, 256, 0, stream>>>();
    cvt_weights_kernel<<<16, 256, 0, stream>>>(d_in[4], d_in[5], d_in[6], d_in[7],
                                               d_in[8], d_in[9], d_in[10], d_in[11]);
    edge_kernel<<<2048, 256, 0, stream>>>(n_raw, e_raw, ei);
    node_kernel<<<512, 256, 0, stream>>>(n_raw, (float*)d_out);
}